// Round 12
// baseline (289.609 us; speedup 1.0000x reference)
//
#include <hip/hip_runtime.h>
#include <math.h>

#define CLS_NUM 16
#define NB 16
#define NH 160
#define NW 160
#define NCH 22          // 6 + CLS_NUM
#define CSZ 25600       // NH*NW plane
#define NT 2048
#define TPB 256
#define NBOXU 1600      // boxes units (256 cells each), bid < NBOXU
#define TILES 40        // 4-row bands per batch
#define NMASKU 640      // 16 batches x 40 bands
#define TCELLS 640      // 4*160 cells per band
#define NBLK (NBOXU + NMASKU)   // 2240
#define CAP 256         // LDS capacity for in-band targets
#define EPS_F 1e-7f

// ws: streamP[NBOXU*16] floats (per-class all-cell -log(1-sc) sums),
//     maskP[NMASKU*64] floats (per class: ao, n_obj, wsub, wide_cnt),
//     counter (1 unsigned, NEVER reset).
// Partials fully rewritten before any read each call (poison-safe).
// Counter: any NBLK consecutive increments contain exactly one value
// == NBLK-1 (mod NBLK), so exactly one winner per call for any start.

__global__ __launch_bounds__(TPB) void detect_fused(
        const float* __restrict__ predict,
        const float* __restrict__ targets,
        float* __restrict__ out,
        float* __restrict__ streamP,
        float* __restrict__ maskP,
        unsigned int* __restrict__ counter)
{
    const int tid = threadIdx.x;
    const int bid = blockIdx.x;

    if (bid < NBOXU) {
        // ============ boxes + per-class all-cells noobj sums (r6 verbatim) ====
        __shared__ float acc_b[16];
        if (tid < 16) acc_b[tid] = 0.f;
        __syncthreads();

        int b = bid / 100;                     // 100 units per batch plane
        int r = (bid % 100) * TPB + tid;       // cell within plane
        const float* pb = predict + (size_t)b * NCH * CSZ + r;
        float p0 = pb[0];
        float p1 = pb[1 * CSZ];
        float p2 = pb[2 * CSZ];
        float p3 = pb[3 * CSZ];
        float p4 = pb[4 * CSZ];
        float p5 = pb[5 * CSZ];
        float raw[16];
        #pragma unroll
        for (int cc = 0; cc < CLS_NUM; cc++) raw[cc] = pb[(6 + cc) * CSZ];

        // argmax on raw logits (sigmoid monotonic; strict > keeps first index)
        float bestraw = raw[0]; int bi = 0;
        #pragma unroll
        for (int cc = 1; cc < CLS_NUM; cc++)
            if (raw[cc] > bestraw) { bestraw = raw[cc]; bi = cc; }

        // streaming: per class, this cell's -log(1-sc); block-reduce
        #pragma unroll
        for (int cc = 0; cc < CLS_NUM; cc++) {
            float s  = 1.0f / (1.0f + __expf(-raw[cc]));
            float sc = fminf(fmaxf(s, EPS_F), 1.0f - EPS_F);
            float v  = -__logf(1.0f - sc);
            #pragma unroll
            for (int o = 32; o > 0; o >>= 1) v += __shfl_down(v, o);
            if ((tid & 63) == 0) atomicAdd(&acc_b[cc], v);
        }

        // boxes output
        float x = 1.0f / (1.0f + __expf(-p0)) * 5.0f - 2.0f;
        float y = 1.0f / (1.0f + __expf(-p1)) * 5.0f - 2.0f;
        float p = 1.0f / (1.0f + __expf(-p4)) * 2.0f - 1.0f;
        float q = 1.0f / (1.0f + __expf(-p5)) * 2.0f - 1.0f;
        float best = 1.0f / (1.0f + __expf(-bestraw));
        float tq = sqrtf((1.0f + p) * 0.5f + 1e-16f);
        float bang = atan2f(q / (2.0f * tq + 1e-16f), tq);
        int i = r / NW, j = r % NW;
        float* o = out + 1 + ((size_t)b * CSZ + r) * 7;
        o[0] = best;
        o[1] = (float)bi;
        o[2] = ((float)j + x) * 8.0f;
        o[3] = ((float)i + y) * 8.0f;
        o[4] = __expf(p2) * 8.0f;
        o[5] = __expf(p3) * 8.0f;
        o[6] = bang;

        __syncthreads();
        if (tid < 16) streamP[bid * 16 + tid] = acc_b[tid];
    } else {
        // ============ mask unit: (batch b, 4-row band), ALL classes (r6) =====
        __shared__ float tg[CAP][8];      // cs,sn,x3,x4,y3,y4,class
        __shared__ float acc_s[64];       // per class: ao, n_obj, wsub, wide_cnt
        __shared__ int cnt_s, pres_s;

        const int u = bid - NBOXU;
        const int b = u / TILES;
        const int band = u - b * TILES;
        const int rb = band * 4;

        if (tid == 0) { cnt_s = 0; pres_s = 0; }
        if (tid < 64) acc_s[tid] = 0.f;
        __syncthreads();

        const float rlo = (float)rb + 0.5f, rhi = (float)rb + 3.5f;
        const float rbc = (float)rb + 2.0f;    // band center y; half-extent 1.5

        for (int n = tid; n < NT; n += TPB) {
            const float* tp = targets + n * 7;
            if ((int)tp[0] == b) {
                float cy = tp[3] * 0.125f;
                float w  = tp[4] * 0.125f, h = tp[5] * 0.125f;
                float R = 0.5f * sqrtf(w * w + h * h) + 0.75f;
                if (cy + R >= rlo && cy - R <= rhi) {
                    float cx = tp[2] * 0.125f;
                    float ang = tp[6];
                    float cs_ = cosf(ang), sn_ = sinf(ang);
                    float xr =  cx * cs_ + cy * sn_;
                    float yr = -cx * sn_ + cy * cs_;
                    float x3 = xr - h * 0.5f, x4 = xr + h * 0.5f;
                    float y3 = yr - w * 0.5f, y4 = yr + w * 0.5f;
                    float acs = fabsf(cs_), asn = fabsf(sn_);
                    float ex = acs * 79.5f + asn * 1.5f + 1e-3f;
                    float ey = acs * 1.5f  + asn * 79.5f + 1e-3f;
                    float vxc = cs_ * 80.0f + sn_ * rbc;
                    float vyc = cs_ * rbc   - sn_ * 80.0f;
                    if (!(vxc + ex < x3 - 0.5f || vxc - ex > x4 + 0.5f ||
                          vyc + ey < y3 - 0.5f || vyc - ey > y4 + 0.5f)) {
                        int slot = atomicAdd(&cnt_s, 1);
                        if (slot < CAP) {
                            tg[slot][0] = cs_; tg[slot][1] = sn_;
                            tg[slot][2] = x3;  tg[slot][3] = x4;
                            tg[slot][4] = y3;  tg[slot][5] = y4;
                            tg[slot][6] = tp[1];
                        }
                    }
                }
            }
        }
        __syncthreads();
        const int cnt = min(cnt_s, CAP);

        // per-cell class masks (bit c = obj, bit 16+c = wide); 3 cells/thread
        float gxa[3], gya[3];
        #pragma unroll
        for (int k = 0; k < 3; k++) {
            int cell = tid + k * TPB;
            gxa[k] = (float)(cell % NW) + 0.5f;
            gya[k] = (float)(rb + cell / NW) + 0.5f;
        }
        unsigned m[3] = {0u, 0u, 0u};
        for (int t = 0; t < cnt; t++) {
            float cs_ = tg[t][0], sn_ = tg[t][1];
            float x3 = tg[t][2], x4 = tg[t][3], y3 = tg[t][4], y4 = tg[t][5];
            int cl = (int)tg[t][6];
            #pragma unroll
            for (int k = 0; k < 3; k++) {
                float vx = cs_ * gxa[k] + sn_ * gya[k];
                float vy = cs_ * gya[k] - sn_ * gxa[k];
                float mn = fminf(fminf(vx - x3, x4 - vx), fminf(vy - y3, y4 - vy));
                unsigned add = (mn >= 0.0f ? 1u : 0u) | (mn >= -0.5f ? 0x10000u : 0u);
                m[k] |= add << cl;
            }
        }
        if (tid >= TCELLS - 2 * TPB) m[2] = 0u;   // cells >= 640 invalid

        unsigned any = m[0] | m[1] | m[2];
        #pragma unroll
        for (int o = 32; o > 0; o >>= 1) any |= (unsigned)__shfl_down((int)any, o);
        if ((tid & 63) == 0) atomicOr(&pres_s, (int)any);
        __syncthreads();
        const unsigned pres = (unsigned)pres_s;

        // sparse corrections, only active classes, only flagged cells
        const float* basec = predict + ((size_t)b * NCH + 6) * CSZ + rb * NW;
        for (int c = 0; c < CLS_NUM; c++) {
            if (!(pres & (0x10000u << c))) continue;   // block-uniform
            const float* cp = basec + (size_t)c * CSZ;
            float ao = 0.f, no = 0.f, wsub = 0.f, wc = 0.f;
            #pragma unroll
            for (int k = 0; k < 3; k++) {
                int cell = tid + k * TPB;
                bool ob = (m[k] >> c) & 1u;
                bool wb = (m[k] >> (16 + c)) & 1u;
                if ((ob | wb) && cell < TCELLS) {
                    float pv = cp[cell];
                    float s  = 1.0f / (1.0f + __expf(-pv));
                    float sc = fminf(fmaxf(s, EPS_F), 1.0f - EPS_F);
                    if (ob) { ao -= __logf(sc);          no += 1.0f; }
                    if (wb) { wsub -= __logf(1.0f - sc); wc += 1.0f; }
                }
            }
            #pragma unroll
            for (int o = 32; o > 0; o >>= 1) {
                ao   += __shfl_down(ao, o);
                no   += __shfl_down(no, o);
                wsub += __shfl_down(wsub, o);
                wc   += __shfl_down(wc, o);
            }
            if ((tid & 63) == 0) {
                atomicAdd(&acc_s[c * 4 + 0], ao);
                atomicAdd(&acc_s[c * 4 + 1], no);
                atomicAdd(&acc_s[c * 4 + 2], wsub);
                atomicAdd(&acc_s[c * 4 + 3], wc);
            }
        }
        __syncthreads();
        if (tid < 64) maskP[u * 64 + tid] = acc_s[tid];
    }

    // ============ last-block loss finalize (1 winner per call) ============
    __shared__ unsigned old_s;
    __threadfence();                      // release: partials visible device-wide
    __syncthreads();                      // all partial writes in block done
    if (tid == 0) old_s = atomicAdd(counter, 1u);
    __syncthreads();
    if ((old_s % (unsigned)NBLK) != (unsigned)(NBLK - 1)) return;

    __threadfence();                      // acquire before reading partials
    __shared__ float st[16][16];          // [group][class]
    __shared__ float mt[4][64];
    __shared__ float S16[16];
    __shared__ float M[64];

    // streamP: 25600 floats; stride 256 (== 0 mod 16) -> class fixed = tid&15
    float s = 0.f;
    for (int i = tid; i < NBOXU * 16; i += TPB) s += streamP[i];
    st[tid >> 4][tid & 15] = s;

    // maskP: 40960 floats; stride 256 (== 0 mod 64) -> component fixed = tid&63
    float sm_ = 0.f;
    for (int i = tid; i < NMASKU * 64; i += TPB) sm_ += maskP[i];
    mt[tid >> 6][tid & 63] = sm_;
    __syncthreads();

    if (tid < 16) {
        float t = 0.f;
        #pragma unroll
        for (int g = 0; g < 16; g++) t += st[g][tid];
        S16[tid] = t;
    } else if (tid >= 64 && tid < 128) {
        int v = tid - 64;
        M[v] = mt[0][v] + mt[1][v] + mt[2][v] + mt[3][v];
    }
    __syncthreads();
    if (tid == 0) {
        float L = 0.f;
        for (int c = 0; c < CLS_NUM; c++) {
            float ao   = M[c * 4 + 0];          // obj loss sum
            float no   = M[c * 4 + 1];          // n_obj
            float wsub = M[c * 4 + 2];          // wide cells' -log(1-sc) sum
            float wc   = M[c * 4 + 3];          // wide cell count
            if (no > 0.f) {
                float nn = 409600.0f - wc;      // n_noobj
                L += ao / fmaxf(no, 1.0f) + (S16[c] - wsub) / fmaxf(nn, 1.0f);
            }
        }
        out[0] = L;
    }
}

extern "C" void kernel_launch(void* const* d_in, const int* in_sizes, int n_in,
                              void* d_out, int out_size, void* d_ws, size_t ws_size,
                              hipStream_t stream) {
    const float* predict = (const float*)d_in[0];
    const float* targets = (const float*)d_in[1];
    float* out = (float*)d_out;

    float* streamP = (float*)d_ws;                  // NBOXU*16
    float* maskP   = streamP + NBOXU * 16;          // NMASKU*64
    unsigned int* counter = (unsigned int*)(maskP + NMASKU * 64);

    detect_fused<<<NBLK, TPB, 0, stream>>>(predict, targets, out,
                                           streamP, maskP, counter);
}

// Round 13
// 58.750 us; speedup vs baseline: 4.9296x; 4.9296x over previous
//
#include <hip/hip_runtime.h>
#include <math.h>

#define CLS_NUM 16
#define NB 16
#define NH 160
#define NW 160
#define NCH 22          // 6 + CLS_NUM
#define CSZ 25600       // NH*NW plane
#define NT 2048
#define TPB 256
#define NBOXU 1600      // boxes units (256 cells each)
#define TILES 40        // 4-row bands per batch
#define NMASKU 640      // 16 batches x 40 bands
#define TCELLS 640      // 4*160 cells per band
#define CAP 256         // LDS capacity for in-band targets
#define EPS_F 1e-7f

// ws: streamP[NBOXU*16] floats (per-class all-cell -log(1-sc) sums),
//     maskP[NMASKU*64] floats (per class: ao, n_obj, wsub, wide_cnt).
// Every slot rewritten each call before any read -> no zeroing, poison-safe.
//
// detect_main is a BYTE-EXACT copy of the round-7 kernel (measured ~24 us);
// only the finalize kernel differs (the 54 us -> ~2 us coalesced version).

__global__ __launch_bounds__(TPB) void detect_main(
        const float* __restrict__ predict,
        const float* __restrict__ targets,
        float* __restrict__ out,
        float* __restrict__ streamP,
        float* __restrict__ maskP)
{
    const int tid = threadIdx.x;
    const int bid = blockIdx.x;

    if (bid < NBOXU) {
        // ============ boxes + streaming per-class noobj-all sums ============
        __shared__ float acc_b[16];
        if (tid < 16) acc_b[tid] = 0.f;
        __syncthreads();

        int b = bid / 100;                     // 100 units per batch plane
        int r = (bid % 100) * TPB + tid;       // cell within plane
        const float* pb = predict + (size_t)b * NCH * CSZ + r;
        float p0 = pb[0];
        float p1 = pb[1 * CSZ];
        float p2 = pb[2 * CSZ];
        float p3 = pb[3 * CSZ];
        float p4 = pb[4 * CSZ];
        float p5 = pb[5 * CSZ];
        float raw[16];
        #pragma unroll
        for (int cc = 0; cc < CLS_NUM; cc++) raw[cc] = pb[(6 + cc) * CSZ];

        // argmax on raw logits (sigmoid monotonic; strict > keeps first index)
        float bestraw = raw[0]; int bi = 0;
        #pragma unroll
        for (int cc = 1; cc < CLS_NUM; cc++)
            if (raw[cc] > bestraw) { bestraw = raw[cc]; bi = cc; }

        // streaming: per class, this cell's -log(1-sc); block-reduce
        #pragma unroll
        for (int cc = 0; cc < CLS_NUM; cc++) {
            float s  = 1.0f / (1.0f + __expf(-raw[cc]));
            float sc = fminf(fmaxf(s, EPS_F), 1.0f - EPS_F);
            float v  = -__logf(1.0f - sc);
            #pragma unroll
            for (int o = 32; o > 0; o >>= 1) v += __shfl_down(v, o);
            if ((tid & 63) == 0) atomicAdd(&acc_b[cc], v);
        }

        // boxes output
        float x = 1.0f / (1.0f + __expf(-p0)) * 5.0f - 2.0f;
        float y = 1.0f / (1.0f + __expf(-p1)) * 5.0f - 2.0f;
        float p = 1.0f / (1.0f + __expf(-p4)) * 2.0f - 1.0f;
        float q = 1.0f / (1.0f + __expf(-p5)) * 2.0f - 1.0f;
        float best = 1.0f / (1.0f + __expf(-bestraw));
        float tq = sqrtf((1.0f + p) * 0.5f + 1e-16f);
        float bang = atan2f(q / (2.0f * tq + 1e-16f), tq);
        int i = r / NW, j = r % NW;
        float* o = out + 1 + ((size_t)b * CSZ + r) * 7;
        o[0] = best;
        o[1] = (float)bi;
        o[2] = ((float)j + x) * 8.0f;
        o[3] = ((float)i + y) * 8.0f;
        o[4] = __expf(p2) * 8.0f;
        o[5] = __expf(p3) * 8.0f;
        o[6] = bang;

        __syncthreads();
        if (tid < 16) streamP[bid * 16 + tid] = acc_b[tid];
        return;
    }

    // ============ mask unit: (batch b, 4-row tile), ALL 16 classes ============
    __shared__ float tg[CAP][8];      // cs,sn,x3,x4,y3,y4,class (pad 8)
    __shared__ float acc_s[64];       // per class: obj_sum, n_obj, wide_sum, wide_cnt
    __shared__ int cnt_s, pres_s;

    const int u = bid - NBOXU;
    const int b = u / TILES;
    const int tile = u - b * TILES;
    const int rb = tile * 4;

    if (tid == 0) { cnt_s = 0; pres_s = 0; }
    if (tid < 64) acc_s[tid] = 0.f;
    __syncthreads();

    const float rlo = (float)rb + 0.5f, rhi = (float)rb + 3.5f;
    const float rbc = (float)rb + 2.0f;   // tile center y; half-extent 1.5

    // gather batch-b targets whose wide box can reach this 4-row band
    for (int n = tid; n < NT; n += TPB) {
        const float* tp = targets + n * 7;
        if ((int)tp[0] == b) {
            float cy = tp[3] * 0.125f;
            float w  = tp[4] * 0.125f, h = tp[5] * 0.125f;
            float R = 0.5f * sqrtf(w * w + h * h) + 0.75f;   // >= wide circumradius
            if (cy + R >= rlo && cy - R <= rhi) {
                float cx = tp[2] * 0.125f;
                float ang = tp[6];
                float cs_ = cosf(ang), sn_ = sinf(ang);
                float xr =  cx * cs_ + cy * sn_;
                float yr = -cx * sn_ + cy * cs_;
                float x3 = xr - h * 0.5f, x4 = xr + h * 0.5f;
                float y3 = yr - w * 0.5f, y4 = yr + w * 0.5f;
                float acs = fabsf(cs_), asn = fabsf(sn_);
                float ex = acs * 79.5f + asn * 1.5f + 1e-3f;
                float ey = acs * 1.5f  + asn * 79.5f + 1e-3f;
                float vxc = cs_ * 80.0f + sn_ * rbc;
                float vyc = cs_ * rbc   - sn_ * 80.0f;
                if (!(vxc + ex < x3 - 0.5f || vxc - ex > x4 + 0.5f ||
                      vyc + ey < y3 - 0.5f || vyc - ey > y4 + 0.5f)) {
                    int slot = atomicAdd(&cnt_s, 1);
                    if (slot < CAP) {
                        tg[slot][0] = cs_; tg[slot][1] = sn_;
                        tg[slot][2] = x3;  tg[slot][3] = x4;
                        tg[slot][4] = y3;  tg[slot][5] = y4;
                        tg[slot][6] = tp[1];
                    }
                }
            }
        }
    }
    __syncthreads();
    const int cnt = min(cnt_s, CAP);

    // per-cell class masks: bit c = obj, bit 16+c = wide (validated r4 packing)
    float gxa[3], gya[3];
    #pragma unroll
    for (int k = 0; k < 3; k++) {
        int cell = tid + k * TPB;
        gxa[k] = (float)(cell % NW) + 0.5f;
        gya[k] = (float)(rb + cell / NW) + 0.5f;
    }
    unsigned m[3] = {0u, 0u, 0u};
    for (int t = 0; t < cnt; t++) {
        float cs_ = tg[t][0], sn_ = tg[t][1];
        float x3 = tg[t][2], x4 = tg[t][3], y3 = tg[t][4], y4 = tg[t][5];
        int cl = (int)tg[t][6];
        #pragma unroll
        for (int k = 0; k < 3; k++) {
            float vx = cs_ * gxa[k] + sn_ * gya[k];
            float vy = cs_ * gya[k] - sn_ * gxa[k];
            float mn = fminf(fminf(vx - x3, x4 - vx), fminf(vy - y3, y4 - vy));
            unsigned add = (mn >= 0.0f ? 1u : 0u) | (mn >= -0.5f ? 0x10000u : 0u);
            m[k] |= add << cl;
        }
    }
    if (tid >= TCELLS - 2 * TPB) m[2] = 0u;   // cells >= 640 invalid

    // block-level class presence (wide bit implies activity; obj subset of wide)
    unsigned any = m[0] | m[1] | m[2];
    #pragma unroll
    for (int o = 32; o > 0; o >>= 1) any |= (unsigned)__shfl_down((int)any, o);
    if ((tid & 63) == 0) atomicOr(&pres_s, (int)any);
    __syncthreads();
    const unsigned pres = (unsigned)pres_s;

    // sparse corrections, only active classes, only flagged cells
    const float* basec = predict + ((size_t)b * NCH + 6) * CSZ + rb * NW;
    for (int c = 0; c < CLS_NUM; c++) {
        if (!(pres & (0x10000u << c))) continue;   // block-uniform
        const float* cp = basec + (size_t)c * CSZ;
        float ao = 0.f, no = 0.f, wsub = 0.f, wc = 0.f;
        #pragma unroll
        for (int k = 0; k < 3; k++) {
            int cell = tid + k * TPB;
            bool ob = (m[k] >> c) & 1u;
            bool wb = (m[k] >> (16 + c)) & 1u;
            if ((ob | wb) && cell < TCELLS) {
                float pv = cp[cell];
                float s  = 1.0f / (1.0f + __expf(-pv));
                float sc = fminf(fmaxf(s, EPS_F), 1.0f - EPS_F);
                if (ob) { ao -= __logf(sc);          no += 1.0f; }
                if (wb) { wsub -= __logf(1.0f - sc); wc += 1.0f; }
            }
        }
        #pragma unroll
        for (int o = 32; o > 0; o >>= 1) {
            ao   += __shfl_down(ao, o);
            no   += __shfl_down(no, o);
            wsub += __shfl_down(wsub, o);
            wc   += __shfl_down(wc, o);
        }
        if ((tid & 63) == 0) {
            atomicAdd(&acc_s[c * 4 + 0], ao);
            atomicAdd(&acc_s[c * 4 + 1], no);
            atomicAdd(&acc_s[c * 4 + 2], wsub);
            atomicAdd(&acc_s[c * 4 + 3], wc);
        }
    }
    __syncthreads();
    if (tid < 64) maskP[u * 64 + tid] = acc_s[tid];
}

// 1 block x 1024 threads: coalesced reduce of both partial arrays -> out[0]
__global__ __launch_bounds__(1024) void finalize_kernel(
        const float* __restrict__ streamP,
        const float* __restrict__ maskP,
        float* __restrict__ out)
{
    __shared__ float st[64][16];   // [row][class]
    __shared__ float mt[16][64];
    __shared__ float S16[16];
    __shared__ float M[64];
    const int tid = threadIdx.x;

    // streamP: 25600 floats; stride 1024 (== 0 mod 16) -> class fixed = tid&15
    float s = 0.f;
    for (int i = tid; i < NBOXU * 16; i += 1024) s += streamP[i];
    st[tid >> 4][tid & 15] = s;

    // maskP: 40960 floats; stride 1024 (== 0 mod 64) -> component fixed = tid&63
    float sm_ = 0.f;
    for (int i = tid; i < NMASKU * 64; i += 1024) sm_ += maskP[i];
    mt[tid >> 6][tid & 63] = sm_;
    __syncthreads();

    if (tid < 16) {
        float t = 0.f;
        #pragma unroll
        for (int rrr = 0; rrr < 64; rrr++) t += st[rrr][tid];
        S16[tid] = t;
    } else if (tid >= 64 && tid < 128) {
        int v = tid - 64;
        float t = 0.f;
        #pragma unroll
        for (int gg = 0; gg < 16; gg++) t += mt[gg][v];
        M[v] = t;
    }
    __syncthreads();
    if (tid == 0) {
        float L = 0.f;
        for (int c = 0; c < CLS_NUM; c++) {
            float ao   = M[c * 4 + 0];          // obj loss sum
            float no   = M[c * 4 + 1];          // n_obj
            float wsub = M[c * 4 + 2];          // wide cells' -log(1-sc) sum
            float wc   = M[c * 4 + 3];          // wide cell count
            if (no > 0.f) {
                float nn = 409600.0f - wc;      // n_noobj
                L += ao / fmaxf(no, 1.0f) + (S16[c] - wsub) / fmaxf(nn, 1.0f);
            }
        }
        out[0] = L;
    }
}

extern "C" void kernel_launch(void* const* d_in, const int* in_sizes, int n_in,
                              void* d_out, int out_size, void* d_ws, size_t ws_size,
                              hipStream_t stream) {
    const float* predict = (const float*)d_in[0];
    const float* targets = (const float*)d_in[1];
    float* out = (float*)d_out;

    float* streamP = (float*)d_ws;                  // NBOXU*16
    float* maskP   = streamP + NBOXU * 16;          // NMASKU*64

    detect_main<<<NBOXU + NMASKU, TPB, 0, stream>>>(predict, targets, out,
                                                    streamP, maskP);
    finalize_kernel<<<1, 1024, 0, stream>>>(streamP, maskP, out);
}

// Round 14
// 51.385 us; speedup vs baseline: 5.6360x; 1.1433x over previous
//
#include <hip/hip_runtime.h>
#include <math.h>

#define CLS_NUM 16
#define NB 16
#define NH 160
#define NW 160
#define NCH 22          // 6 + CLS_NUM
#define CSZ 25600       // NH*NW plane
#define NT 2048
#define TPB 256
#define KC 10           // cells per thread in boxes path
#define NBOXB 160       // boxes blocks: 10 per batch plane, 2560 cells each
#define TILES 40        // 4-row bands per batch
#define NMASKU 640      // 16 batches x 40 bands
#define TCELLS 640      // 4*160 cells per band
#define CAP 256         // LDS capacity for in-band targets
#define EPS_F 1e-7f
#define CLIPV 16.118096f   // -log(1e-7)

// ws: streamP[NBOXB*16] floats (per-class all-cell -log(1-sc) sums),
//     maskP[NMASKU*64] floats (per class: ao, n_obj, wsub, wide_cnt).
// Every slot rewritten each call before any read -> no zeroing, poison-safe.

__global__ __launch_bounds__(TPB) void detect_main(
        const float* __restrict__ predict,
        const float* __restrict__ targets,
        float* __restrict__ out,
        float* __restrict__ streamP,
        float* __restrict__ maskP)
{
    const int tid = threadIdx.x;
    const int bid = blockIdx.x;

    if (bid < NBOXB) {
        // ===== boxes + per-class noobj-all sums, 10 cells/thread =====
        __shared__ float acc_b[16];
        if (tid < 16) acc_b[tid] = 0.f;
        __syncthreads();

        const int b = bid / 10;                 // 10 blocks per batch plane
        const int rbase = (bid % 10) * (KC * TPB);
        const float* pbase = predict + (size_t)b * NCH * CSZ;

        float anS[16];
        #pragma unroll
        for (int cc = 0; cc < CLS_NUM; cc++) anS[cc] = 0.f;

        #pragma unroll 2
        for (int k = 0; k < KC; k++) {
            const int r = rbase + k * TPB + tid;
            const float* pb = pbase + r;

            // fused: argmax on raw logits + per-class softplus accumulation
            float bestraw = -INFINITY; int bi = 0;
            #pragma unroll
            for (int cc = 0; cc < CLS_NUM; cc++) {
                float pv = pb[(6 + cc) * CSZ];
                if (pv > bestraw) { bestraw = pv; bi = cc; }  // strict >: first idx
                // -log(1-clip(sigmoid(pv))) == min(softplus(pv), CLIPV)
                anS[cc] += fminf(__logf(1.0f + __expf(pv)), CLIPV);
            }

            float p0 = pb[0];
            float p1 = pb[1 * CSZ];
            float p2 = pb[2 * CSZ];
            float p3 = pb[3 * CSZ];
            float p4 = pb[4 * CSZ];
            float p5 = pb[5 * CSZ];
            float x = 1.0f / (1.0f + __expf(-p0)) * 5.0f - 2.0f;
            float y = 1.0f / (1.0f + __expf(-p1)) * 5.0f - 2.0f;
            float p = 1.0f / (1.0f + __expf(-p4)) * 2.0f - 1.0f;
            float q = 1.0f / (1.0f + __expf(-p5)) * 2.0f - 1.0f;
            float best = 1.0f / (1.0f + __expf(-bestraw));    // sigmoid monotonic
            float tq = sqrtf((1.0f + p) * 0.5f + 1e-16f);
            float bang = atan2f(q / (2.0f * tq + 1e-16f), tq);
            int i = r / NW, j = r % NW;
            float* o = out + 1 + ((size_t)b * CSZ + r) * 7;
            o[0] = best;
            o[1] = (float)bi;
            o[2] = ((float)j + x) * 8.0f;
            o[3] = ((float)i + y) * 8.0f;
            o[4] = __expf(p2) * 8.0f;
            o[5] = __expf(p3) * 8.0f;
            o[6] = bang;
        }

        // ONE reduction per thread for all 10 cells: 16 classes x 6 shfl
        #pragma unroll
        for (int cc = 0; cc < CLS_NUM; cc++) {
            float v = anS[cc];
            #pragma unroll
            for (int o = 32; o > 0; o >>= 1) v += __shfl_down(v, o);
            if ((tid & 63) == 0) atomicAdd(&acc_b[cc], v);
        }
        __syncthreads();
        if (tid < 16) streamP[bid * 16 + tid] = acc_b[tid];
        return;
    }

    // ============ mask unit: (batch b, 4-row band), ALL 16 classes ============
    __shared__ float tg[CAP][8];      // cs,sn,x3,x4,y3,y4,class
    __shared__ float acc_s[64];       // per class: ao, n_obj, wsub, wide_cnt
    __shared__ int cnt_s, pres_s;

    const int u = bid - NBOXB;
    const int b = u / TILES;
    const int band = u - b * TILES;
    const int rb = band * 4;

    if (tid == 0) { cnt_s = 0; pres_s = 0; }
    if (tid < 64) acc_s[tid] = 0.f;
    __syncthreads();

    const float rlo = (float)rb + 0.5f, rhi = (float)rb + 3.5f;
    const float rbc = (float)rb + 2.0f;   // band center y; half-extent 1.5

    // gather batch-b targets whose wide box can reach this 4-row band
    for (int n = tid; n < NT; n += TPB) {
        const float* tp = targets + n * 7;
        if ((int)tp[0] == b) {
            float cy = tp[3] * 0.125f;
            float w  = tp[4] * 0.125f, h = tp[5] * 0.125f;
            float R = 0.5f * sqrtf(w * w + h * h) + 0.75f;   // >= wide circumradius
            if (cy + R >= rlo && cy - R <= rhi) {
                float cx = tp[2] * 0.125f;
                float ang = tp[6];
                float cs_ = cosf(ang), sn_ = sinf(ang);
                float xr =  cx * cs_ + cy * sn_;
                float yr = -cx * sn_ + cy * cs_;
                float x3 = xr - h * 0.5f, x4 = xr + h * 0.5f;
                float y3 = yr - w * 0.5f, y4 = yr + w * 0.5f;
                float acs = fabsf(cs_), asn = fabsf(sn_);
                float ex = acs * 79.5f + asn * 1.5f + 1e-3f;
                float ey = acs * 1.5f  + asn * 79.5f + 1e-3f;
                float vxc = cs_ * 80.0f + sn_ * rbc;
                float vyc = cs_ * rbc   - sn_ * 80.0f;
                if (!(vxc + ex < x3 - 0.5f || vxc - ex > x4 + 0.5f ||
                      vyc + ey < y3 - 0.5f || vyc - ey > y4 + 0.5f)) {
                    int slot = atomicAdd(&cnt_s, 1);
                    if (slot < CAP) {
                        tg[slot][0] = cs_; tg[slot][1] = sn_;
                        tg[slot][2] = x3;  tg[slot][3] = x4;
                        tg[slot][4] = y3;  tg[slot][5] = y4;
                        tg[slot][6] = tp[1];
                    }
                }
            }
        }
    }
    __syncthreads();
    const int cnt = min(cnt_s, CAP);

    // per-cell class masks: bit c = obj, bit 16+c = wide; 3 cells/thread
    float gxa[3], gya[3];
    #pragma unroll
    for (int k = 0; k < 3; k++) {
        int cell = tid + k * TPB;
        gxa[k] = (float)(cell % NW) + 0.5f;
        gya[k] = (float)(rb + cell / NW) + 0.5f;
    }
    unsigned m[3] = {0u, 0u, 0u};
    for (int t = 0; t < cnt; t++) {
        float cs_ = tg[t][0], sn_ = tg[t][1];
        float x3 = tg[t][2], x4 = tg[t][3], y3 = tg[t][4], y4 = tg[t][5];
        int cl = (int)tg[t][6];
        #pragma unroll
        for (int k = 0; k < 3; k++) {
            float vx = cs_ * gxa[k] + sn_ * gya[k];
            float vy = cs_ * gya[k] - sn_ * gxa[k];
            float mn = fminf(fminf(vx - x3, x4 - vx), fminf(vy - y3, y4 - vy));
            unsigned add = (mn >= 0.0f ? 1u : 0u) | (mn >= -0.5f ? 0x10000u : 0u);
            m[k] |= add << cl;
        }
    }
    if (tid >= TCELLS - 2 * TPB) m[2] = 0u;   // cells >= 640 invalid

    unsigned any = m[0] | m[1] | m[2];
    #pragma unroll
    for (int o = 32; o > 0; o >>= 1) any |= (unsigned)__shfl_down((int)any, o);
    if ((tid & 63) == 0) atomicOr(&pres_s, (int)any);
    __syncthreads();
    const unsigned pres = (unsigned)pres_s;

    // sparse corrections, only active classes, only flagged cells
    const float* basec = predict + ((size_t)b * NCH + 6) * CSZ + rb * NW;
    for (int c = 0; c < CLS_NUM; c++) {
        if (!(pres & (0x10000u << c))) continue;   // block-uniform
        const float* cp = basec + (size_t)c * CSZ;
        float ao = 0.f, no = 0.f, wsub = 0.f, wc = 0.f;
        #pragma unroll
        for (int k = 0; k < 3; k++) {
            int cell = tid + k * TPB;
            bool ob = (m[k] >> c) & 1u;
            bool wb = (m[k] >> (16 + c)) & 1u;
            if ((ob | wb) && cell < TCELLS) {
                float pv = cp[cell];
                float s  = 1.0f / (1.0f + __expf(-pv));
                float sc = fminf(fmaxf(s, EPS_F), 1.0f - EPS_F);
                if (ob) { ao -= __logf(sc);          no += 1.0f; }
                if (wb) { wsub -= __logf(1.0f - sc); wc += 1.0f; }
            }
        }
        #pragma unroll
        for (int o = 32; o > 0; o >>= 1) {
            ao   += __shfl_down(ao, o);
            no   += __shfl_down(no, o);
            wsub += __shfl_down(wsub, o);
            wc   += __shfl_down(wc, o);
        }
        if ((tid & 63) == 0) {
            atomicAdd(&acc_s[c * 4 + 0], ao);
            atomicAdd(&acc_s[c * 4 + 1], no);
            atomicAdd(&acc_s[c * 4 + 2], wsub);
            atomicAdd(&acc_s[c * 4 + 3], wc);
        }
    }
    __syncthreads();
    if (tid < 64) maskP[u * 64 + tid] = acc_s[tid];
}

// 1 block x 1024 threads: coalesced reduce of both partial arrays -> out[0]
__global__ __launch_bounds__(1024) void finalize_kernel(
        const float* __restrict__ streamP,
        const float* __restrict__ maskP,
        float* __restrict__ out)
{
    __shared__ float st[64][16];   // [row][class]
    __shared__ float mt[16][64];
    __shared__ float S16[16];
    __shared__ float M[64];
    const int tid = threadIdx.x;

    // streamP: 2560 floats; stride 1024 (== 0 mod 16) -> class fixed = tid&15
    float s = 0.f;
    for (int i = tid; i < NBOXB * 16; i += 1024) s += streamP[i];
    st[tid >> 4][tid & 15] = s;

    // maskP: 40960 floats; stride 1024 (== 0 mod 64) -> component fixed = tid&63
    float sm_ = 0.f;
    for (int i = tid; i < NMASKU * 64; i += 1024) sm_ += maskP[i];
    mt[tid >> 6][tid & 63] = sm_;
    __syncthreads();

    if (tid < 16) {
        float t = 0.f;
        #pragma unroll
        for (int rrr = 0; rrr < 64; rrr++) t += st[rrr][tid];
        S16[tid] = t;
    } else if (tid >= 64 && tid < 128) {
        int v = tid - 64;
        float t = 0.f;
        #pragma unroll
        for (int gg = 0; gg < 16; gg++) t += mt[gg][v];
        M[v] = t;
    }
    __syncthreads();
    if (tid == 0) {
        float L = 0.f;
        for (int c = 0; c < CLS_NUM; c++) {
            float ao   = M[c * 4 + 0];          // obj loss sum
            float no   = M[c * 4 + 1];          // n_obj
            float wsub = M[c * 4 + 2];          // wide cells' -log(1-sc) sum
            float wc   = M[c * 4 + 3];          // wide cell count
            if (no > 0.f) {
                float nn = 409600.0f - wc;      // n_noobj
                L += ao / fmaxf(no, 1.0f) + (S16[c] - wsub) / fmaxf(nn, 1.0f);
            }
        }
        out[0] = L;
    }
}

extern "C" void kernel_launch(void* const* d_in, const int* in_sizes, int n_in,
                              void* d_out, int out_size, void* d_ws, size_t ws_size,
                              hipStream_t stream) {
    const float* predict = (const float*)d_in[0];
    const float* targets = (const float*)d_in[1];
    float* out = (float*)d_out;

    float* streamP = (float*)d_ws;                  // NBOXB*16
    float* maskP   = streamP + NBOXB * 16;          // NMASKU*64

    detect_main<<<NBOXB + NMASKU, TPB, 0, stream>>>(predict, targets, out,
                                                    streamP, maskP);
    finalize_kernel<<<1, 1024, 0, stream>>>(streamP, maskP, out);
}